// Round 3
// 82.856 us; speedup vs baseline: 1.0021x; 1.0021x over previous
//
#include <hip/hip_runtime.h>
#include <hip/hip_bf16.h>

// SwitchLinear: out[b,o] = sum_i x[b,i]*W[o,i,c_b] + bias[o,c_b]
// x,W,bias,out = fp32; idx = int32. B=8192 I=O=256 C=32.
// R10 = R9 with the REAL bug fixed: tile row = 512B = 32 x 16B slots; R8/R9
// decomposed slots as 16/row (row = lin16>>4) -> staging rows ran 0..127 ->
// blist[64..127] LDS-OOB -> garbage gather rows -> wild global addr -> abort.
// Correct: row = s*8 + (tid>>5), p = tid&31. Swizzle = G4 pattern:
// position p holds element p ^ (row&7)  (byte ^= (row&7)<<4);
// stage source e16 = (tid&31) ^ (tid>>5); read kx ^= (lrc&7)<<4.
// Design (from R8): xbf = x pre-converted to bf16 in k_prep (4MB); single
// K=256 stage via global_load_lds w=16 (wave-uniform dest); 3 barriers/mt.
// History: R4 coop launch rejected; R6 single-dispatch handshake +21us;
// R7 per-lane A gather +18us. R5+micro-opts = 83.0us baseline.
#define NB 8192
#define NI 256
#define NO 256
#define NC 32

typedef __attribute__((ext_vector_type(8))) short short8;   // 8 x bf16
typedef __attribute__((ext_vector_type(4))) float floatx4;  // MFMA acc

// ---- workspace layout (bytes) ----
#define WS_COUNTS_OFF 0            // uint counts[NC]
#define WS_LISTS_OFF  (4u << 10)   // ushort lists[NC][NB]  (512 KB)
#define WS_WT_OFF     (1u << 20)   // ushort wT[NC][NO][NI] (4 MB)
#define WS_XBF_OFF    (5u << 20)   // ushort xbf[NB][NI]    (4 MB)

static __device__ __forceinline__ unsigned short f2bf(float f) {
    __hip_bfloat16 h = __float2bfloat16(f);   // RNE
    return *(unsigned short*)&h;
}

// async global->LDS, 16B per lane; LDS dest is wave-uniform base;
// HW writes base + lane*16 (m104/m108). Source address is per-lane.
static __device__ __forceinline__ void gload_lds16(const void* g, void* l) {
    __builtin_amdgcn_global_load_lds(
        (const __attribute__((address_space(1))) unsigned int*)g,
        (__attribute__((address_space(3))) unsigned int*)l,
        16, 0, 0);
}

// prep grid: [0,128) transpose W -> wT bf16; [128,160) bucket channels;
//            [160,416) convert x fp32 -> bf16 (32 elems/thread)
#define PREP_TRAN 128
#define PREP_XCONV 256
#define PREP_BLOCKS (PREP_TRAN + NC + PREP_XCONV)

__global__ __launch_bounds__(256) void k_prep(
        const int* __restrict__ idx,
        const float* __restrict__ w,
        const float* __restrict__ x,
        unsigned int* __restrict__ counts,
        unsigned short* __restrict__ lists,
        unsigned short* __restrict__ wT,
        unsigned short* __restrict__ xbf) {
    const int bid = blockIdx.x;
    const int tid = threadIdx.x;

    if (bid < PREP_TRAN) {
        // thread handles g0 = 2*(bid*256+tid) and g0+1  (g = o*NI + i)
        int g0 = (bid * 256 + tid) * 2;
        const float4* s0 = (const float4*)(w + (size_t)g0 * NC);
        unsigned short v0[NC], v1[NC];
#pragma unroll
        for (int s = 0; s < 8; ++s) {
            float4 a = s0[s];
            v0[s * 4 + 0] = f2bf(a.x); v0[s * 4 + 1] = f2bf(a.y);
            v0[s * 4 + 2] = f2bf(a.z); v0[s * 4 + 3] = f2bf(a.w);
        }
#pragma unroll
        for (int s = 0; s < 8; ++s) {
            float4 a = s0[8 + s];
            v1[s * 4 + 0] = f2bf(a.x); v1[s * 4 + 1] = f2bf(a.y);
            v1[s * 4 + 2] = f2bf(a.z); v1[s * 4 + 3] = f2bf(a.w);
        }
#pragma unroll
        for (int c = 0; c < NC; ++c) {
            // fixed c: 64 lanes x 4 B = 256 B contiguous store per wave-instr
            unsigned short pair[2] = {v0[c], v1[c]};
            *(unsigned int*)(wT + (size_t)c * (NO * NI) + g0) = *(unsigned int*)pair;
        }
    } else if (bid < PREP_TRAN + NC) {
        __shared__ unsigned int lcnt;
        const int c = bid - PREP_TRAN;
        if (tid == 0) lcnt = 0u;
        __syncthreads();
        const int4* idx4 = (const int4*)idx;
        for (int t = tid; t < NB / 4; t += 256) {
            int4 v = idx4[t];
            int b0 = t * 4;
            if (v.x == c) lists[c * NB + atomicAdd(&lcnt, 1u)] = (unsigned short)(b0 + 0);
            if (v.y == c) lists[c * NB + atomicAdd(&lcnt, 1u)] = (unsigned short)(b0 + 1);
            if (v.z == c) lists[c * NB + atomicAdd(&lcnt, 1u)] = (unsigned short)(b0 + 2);
            if (v.w == c) lists[c * NB + atomicAdd(&lcnt, 1u)] = (unsigned short)(b0 + 3);
        }
        __syncthreads();
        if (tid == 0) counts[c] = lcnt;
    } else {
        // x fp32 -> bf16: 32 elems/thread, 256 blocks covers 8192*256
        int t = (bid - PREP_TRAN - NC) * 256 + tid;      // 0..65535
        const float4* src = (const float4*)(x + (size_t)t * 32);
        __attribute__((aligned(16))) unsigned short v[32];
#pragma unroll
        for (int s = 0; s < 8; ++s) {
            float4 a = src[s];
            v[s * 4 + 0] = f2bf(a.x); v[s * 4 + 1] = f2bf(a.y);
            v[s * 4 + 2] = f2bf(a.z); v[s * 4 + 3] = f2bf(a.w);
        }
        uint4* dst = (uint4*)(xbf + (size_t)t * 32);
#pragma unroll
        for (int s = 0; s < 4; ++s) dst[s] = ((const uint4*)v)[s];
    }
}

// Grouped GEMM: grid (c, o-tile, z=4), block = 256 = 4 waves, persistent in m.
// Tile M=64, N=64, K=256 staged in ONE shot via global_load_lds (16B/lane).
// LDS [64][256] bf16 (512 B/row = 32 x 16B slots). Swizzled content:
// 16B-slot position (row, p) holds element (row, p ^ (row&7)).
// Staging: slot lin16 = s*256 + tid -> row = s*8 + (tid>>5), p = tid&31,
//          row&7 = tid>>5 (thread-constant) -> src e16 = (tid&31)^(tid>>5).
//          Wave-uniform dest base = (s*2048 + wv*512) ushorts.
// Read: fragment slot e = k0*4 + hi; read position p = e ^ (lrc&7)
//       -> byte kx = (k0*64 | hi*16) ^ ((lrc&7)<<4). Rows ms*16+lrc /
//       wv*16+lrc both have row&7 = lrc&7. 8 lanes per 4-bank window.
__launch_bounds__(256)
__global__ void k_gemm(const unsigned short* __restrict__ xbf,
                       const unsigned short* __restrict__ wT,
                       const float* __restrict__ bias,
                       const unsigned int* __restrict__ counts,
                       const unsigned short* __restrict__ lists,
                       float* __restrict__ out) {
    const int c  = blockIdx.x;
    const int o0 = blockIdx.y * 64;
    const int cnt = (int)counts[c];

    __shared__ unsigned short As[64 * 256];   // 32 KB, swizzled content
    __shared__ unsigned short Bs[64 * 256];   // 32 KB
    __shared__ int blist[64];

    const int tid  = threadIdx.x;
    const int wv   = tid >> 6;
    const int lane = tid & 63;
    const int lrc  = lane & 15;        // A row m / B row n / D col
    const int hi   = lane >> 4;
    const int hi16 = hi * 16;          // byte offset of k-subgroup within 64B
    const int X    = (lrc & 7) << 4;   // read-side swizzle XOR (bytes)
    const int rbase = hi * 4;

    const unsigned short* wTc = wT + ((size_t)c * NO + o0) * NI;
    const int o = o0 + wv * 16 + lrc;
    const float bv = bias[o * NC + c];

    // staging geometry (per-lane SOURCE, wave-uniform DEST), 8 slots/thread:
    const int prow = tid >> 5;                  // row&7 for all s (0..7)
    const int e16  = (tid & 31) ^ prow;         // source 16B-slot within row
    const unsigned short* bsrc0 = wTc + prow * NI + e16 * 8;   // + s*2048
    const int dbase = wv * 512;                 // + s*2048 (ushorts)

    for (int mt = blockIdx.z; mt * 64 < cnt; mt += 4) {
        const int m0 = mt * 64;
        if (tid < 64) {
            int mr = m0 + tid;
            blist[tid] = (int)lists[c * NB + (mr < cnt ? mr : m0)];
        }
        __syncthreads();

        // ---- stage B: 8 x 16B per thread (rows s*8+prow, 64 rows total)
#pragma unroll
        for (int s = 0; s < 8; ++s)
            gload_lds16(bsrc0 + s * 2048, Bs + dbase + s * 2048);
        // ---- stage A: gathered bf16 rows of xbf
#pragma unroll
        for (int s = 0; s < 8; ++s) {
            gload_lds16(xbf + (size_t)blist[s * 8 + prow] * NI + e16 * 8,
                        As + dbase + s * 2048);
        }
        __syncthreads();   // compiler drains vmcnt(0) here -> tiles resident

        floatx4 acc[4];
#pragma unroll
        for (int ms = 0; ms < 4; ++ms) acc[ms] = (floatx4){0.f, 0.f, 0.f, 0.f};

        const char* Ab = (const char*)As;
        const char* Bb = (const char*)Bs;
        const int nrow = wv * 16 + lrc;
#pragma unroll
        for (int k0 = 0; k0 < 8; ++k0) {
            const int kx = ((k0 * 64) | hi16) ^ X;   // swizzled k-byte offset
            short8 bfrag = *(const short8*)(Bb + nrow * 512 + kx);
#pragma unroll
            for (int ms = 0; ms < 4; ++ms) {
                short8 afrag = *(const short8*)(Ab + (ms * 16 + lrc) * 512 + kx);
                acc[ms] = __builtin_amdgcn_mfma_f32_16x16x32_bf16(afrag, bfrag, acc[ms], 0, 0, 0);
            }
        }

        // D layout: col = lane&15, row = (lane>>4)*4 + reg
#pragma unroll
        for (int ms = 0; ms < 4; ++ms) {
#pragma unroll
            for (int r = 0; r < 4; ++r) {
                int row = ms * 16 + rbase + r;
                if (m0 + row < cnt) {
                    out[(size_t)blist[row] * NO + o] = acc[ms][r] + bv;
                }
            }
        }
        __syncthreads();   // protect blist/As/Bs for next persistent iteration
    }
}

extern "C" void kernel_launch(void* const* d_in, const int* in_sizes, int n_in,
                              void* d_out, int out_size, void* d_ws, size_t ws_size,
                              hipStream_t stream) {
    const float* x    = (const float*)d_in[0];   // fp32 [NB][NI]
    const int*   idx  = (const int*)d_in[1];     // int32 [NB]
    const float* w    = (const float*)d_in[2];   // fp32 [NO][NI][NC]
    const float* bias = (const float*)d_in[3];   // fp32 [NO][NC]
    float* out = (float*)d_out;                  // fp32 [NB][NO]

    char* ws = (char*)d_ws;
    unsigned int*   counts = (unsigned int*)(ws + WS_COUNTS_OFF);
    unsigned short* lists  = (unsigned short*)(ws + WS_LISTS_OFF);
    unsigned short* wT     = (unsigned short*)(ws + WS_WT_OFF);
    unsigned short* xbf    = (unsigned short*)(ws + WS_XBF_OFF);

    k_prep<<<PREP_BLOCKS, 256, 0, stream>>>(idx, w, x, counts, lists, wT, xbf);
    dim3 grid(NC, NO / 64, 4);
    k_gemm<<<grid, 256, 0, stream>>>(xbf, wT, bias, counts, lists, out);
}